// Round 3
// baseline (128.748 us; speedup 1.0000x reference)
//
#include <hip/hip_runtime.h>
#include <math.h>

#define BB 64
#define HH 30
#define WW 60
#define DD 64
#define NPIX 1800

// 16 col-bands (common refinement of 6/10/15-wide cols), 8 row-bands (of 6/10/15-tall rows)
__constant__ int c_colband[WW] = {0,0,0,0,0,0, 1,1,1,1, 2,2, 3,3,3, 4,4,4, 5,5, 6,6,6,6, 7,7,7,7,7,7,
                                  8,8,8,8,8,8, 9,9,9,9, 10,10, 11,11,11, 12,12,12, 13,13, 14,14,14,14, 15,15,15,15,15,15};
__constant__ int c_band_start[8] = {0,6,10,12,15,18,20,24};
__constant__ int c_band_cnt[8]   = {6,4,2,3,3,2,4,6};
// 20 column-region outputs (10 s0 + 6 s1 + 4 s2) composed from colband quarters
__constant__ int c_first[20] = {0,1,3,5,7,8,9,11,13,15, 0,2,6,8,10,14, 0,4,8,12};
__constant__ int c_cnt[20]   = {1,2,2,2,1,1,2,2,2,1,   2,4,2,2,4,2,   4,4,4,4};
// colband -> s0/s1 col-region index
__constant__ int c_s0col[16] = {0,1,1,2,2,3,3,4,5,6,6,7,7,8,8,9};
__constant__ int c_s1col[16] = {0,0,1,1,1,1,2,2,3,3,4,4,4,4,5,5};
// row-region -> row-band composition
__constant__ int c_s0bf[5] = {0,1,3,5,7};
__constant__ int c_s0bc[5] = {1,2,2,2,1};
__constant__ int c_s1bf[3] = {0,2,6};
__constant__ int c_s1bc[3] = {2,4,2};
__constant__ int c_s2bf[2] = {0,4};

// ---------------- K1: band pooling of x (blocks 0..511) + E/u/v/s (blocks 512..575) ----------------
// pooling block = (b, band): sums x over the band's rows into 20 col-region vectors (no atomics).
// E^T[e][d] = sum_j Wq[j][d]*Wk[j][e]   (stored e-major so K2 reads columns coalesced/conflict-free)
__global__ __launch_bounds__(256) void k1_pool_E(
    const float* __restrict__ x, const float* __restrict__ qk_w,
    const float* __restrict__ qk_b, float* __restrict__ bandsums,
    float* __restrict__ ET_ws, float* __restrict__ u_ws,
    float* __restrict__ v_ws, float* __restrict__ s_ws)
{
    const int t = threadIdx.x;

    if (blockIdx.x >= 512) {
        const int e = blockIdx.x - 512;
        if (t < 64) {   // ET row e: lane d
            float acc = 0.f;
#pragma unroll 8
            for (int jj = 0; jj < 64; ++jj)
                acc += qk_w[jj * 64 + t] * qk_w[(64 + e) * 64 + jj];  // Wq[jj][t] * Wk[e][jj]... see note
            // NOTE: Wk[j][e] means row (64+j), col e of qk_w. Correct form below:
            acc = 0.f;
#pragma unroll 8
            for (int jj = 0; jj < 64; ++jj)
                acc += qk_w[jj * 64 + t] * qk_w[(64 + jj) * 64 + e];
            ET_ws[e * 64 + t] = acc;
        } else if (e == 0 && t >= 64 && t < 128) {   // u[d] = sum_j Wq[j][d]*bk[j]
            const int d = t - 64;
            float acc = 0.f;
            for (int jj = 0; jj < 64; ++jj) acc += qk_w[jj * 64 + d] * qk_b[64 + jj];
            u_ws[d] = acc;
        } else if (e == 0 && t >= 128 && t < 192) {  // v[e2] = sum_j Wk[j][e2]*bq[j]
            const int e2 = t - 128;
            float acc = 0.f;
            for (int jj = 0; jj < 64; ++jj) acc += qk_w[(64 + jj) * 64 + e2] * qk_b[jj];
            v_ws[e2] = acc;
        } else if (e == 0 && t == 192) {             // s = bq . bk
            float acc = 0.f;
            for (int jj = 0; jj < 64; ++jj) acc += qk_b[jj] * qk_b[64 + jj];
            s_ws[0] = acc;
        }
        return;
    }

    __shared__ float pools[16 * 64];
    const int b = blockIdx.x >> 3;
    const int band = blockIdx.x & 7;
    const int j = t & 63;
    const int g = t >> 6;
    const int h0 = c_band_start[band];
    const int nr = c_band_cnt[band];

    float A0 = 0.f, A1 = 0.f, A2 = 0.f, A3 = 0.f;
    for (int r = 0; r < nr; ++r) {
        const float* xrow = x + ((size_t)(b * NPIX + (h0 + r) * WW) + g * 15) * DD;
        float v[15];
#pragma unroll
        for (int i = 0; i < 15; ++i) v[i] = xrow[i * DD + j];
        if ((g & 1) == 0) {   // colband widths 6,4,2,3 within this quarter
            A0 += ((v[0]+v[1])+(v[2]+v[3]))+(v[4]+v[5]);
            A1 += (v[6]+v[7])+(v[8]+v[9]);
            A2 += v[10]+v[11];
            A3 += (v[12]+v[13])+v[14];
        } else {              // widths 3,2,4,6
            A0 += (v[0]+v[1])+v[2];
            A1 += v[3]+v[4];
            A2 += (v[5]+v[6])+(v[7]+v[8]);
            A3 += ((v[9]+v[10])+(v[11]+v[12]))+(v[13]+v[14]);
        }
    }
    pools[(g * 4 + 0) * 64 + j] = A0;
    pools[(g * 4 + 1) * 64 + j] = A1;
    pools[(g * 4 + 2) * 64 + j] = A2;
    pools[(g * 4 + 3) * 64 + j] = A3;
    __syncthreads();

    float* outp = bandsums + (((size_t)b * 8 + band) * 20) * 64;
    for (int i = t; i < 20 * 64; i += 256) {
        const int c = i >> 6, d = i & 63;
        const int f = c_first[c], n = c_cnt[c];
        float s = 0.f;
        for (int q = 0; q < n; ++q) s += pools[(f + q) * 64 + d];
        outp[i] = s;
    }
}

// ---------------- K2: per-row G via E, fused dot + gumbel mask ----------------
// grid = BB*HH, block = 256
__global__ __launch_bounds__(256) void k2_mask(
    const float* __restrict__ x, const float* __restrict__ score_w,
    const float* __restrict__ score_b, const float* __restrict__ bandsums,
    const float* __restrict__ ET_ws, const float* __restrict__ u_ws,
    const float* __restrict__ v_ws, const float* __restrict__ s_ws,
    const float* __restrict__ noise_x, const float* __restrict__ noise_r,
    float* __restrict__ out)
{
    __shared__ float ET[64 * 64];   // 16 KB, e-major: ET[e*64+d]
    __shared__ float R[20 * 64];    // 5 KB col-region sums for this row's row-regions
    __shared__ float XC[16 * 64];   // 4 KB xcomb per colband-cell
    __shared__ float Gl[16 * 64];   // 4 KB
    __shared__ float ul[64], vl[64];
    __shared__ float crow[16];
    __shared__ float attnv[64];

    const int b = blockIdx.x / HH;
    const int h = blockIdx.x % HH;
    const int t = threadIdx.x;
    const int lane = t & 63;
    const int g = t >> 6;

    for (int i = t; i < 4096; i += 256) ET[i] = ET_ws[i];
    if (t < 64) ul[t] = u_ws[t];
    else if (t < 128) vl[t - 64] = v_ws[t - 64];

    const int s0r = h / 6, s1r = h / 10, s2r = h / 15;
    const float* bs = bandsums + (size_t)b * 8 * 20 * 64;
    for (int i = t; i < 20 * 64; i += 256) {
        const int c = i >> 6;
        int f, n;
        if (c < 10)      { f = c_s0bf[s0r]; n = c_s0bc[s0r]; }
        else if (c < 16) { f = c_s1bf[s1r]; n = c_s1bc[s1r]; }
        else             { f = c_s2bf[s2r]; n = 4; }
        float s = 0.f;
        for (int q = 0; q < n; ++q) s += bs[((size_t)(f + q) * 20) * 64 + i];
        R[i] = s;
    }
    __syncthreads();

    const float w0n = score_w[0] * (1.0f / 36.0f);
    const float w1n = score_w[1] * (1.0f / 100.0f);
    const float w2n = score_w[2] * (1.0f / 225.0f);
    for (int i = t; i < 16 * 64; i += 256) {
        const int cb = i >> 6, d = i & 63;
        XC[i] = w0n * R[c_s0col[cb] * 64 + d]
              + w1n * R[(10 + c_s1col[cb]) * 64 + d]
              + w2n * R[(16 + (cb >> 2)) * 64 + d];
    }
    __syncthreads();

    // G phase: wave g owns cells 4g..4g+3. Rank-1 accumulation over e:
    //   G[cg][lane] += ET[e][lane] * XC[cg][e]   (XC[cg][e] via readlane of xfrag)
    {
        const float wsum = score_w[0] + score_w[1] + score_w[2];
        const float sv = s_ws[0];
        const float sb = score_b[0];
        float xfrag[4], acc[4];
#pragma unroll
        for (int ci = 0; ci < 4; ++ci) {
            xfrag[ci] = XC[(g * 4 + ci) * 64 + lane];
            acc[ci] = 0.f;
        }
#pragma unroll 16
        for (int e = 0; e < 64; ++e) {
            const float ecol = ET[e * 64 + lane];   // conflict-free
#pragma unroll
            for (int ci = 0; ci < 4; ++ci)
                acc[ci] += ecol * __shfl(xfrag[ci], e, 64);
        }
#pragma unroll
        for (int ci = 0; ci < 4; ++ci) {
            const int cg = g * 4 + ci;
            Gl[cg * 64 + lane] = 0.125f * (acc[ci] + wsum * ul[lane]);
            float pv = vl[lane] * xfrag[ci];
            pv += __shfl_xor(pv, 1, 64);  pv += __shfl_xor(pv, 2, 64);
            pv += __shfl_xor(pv, 4, 64);  pv += __shfl_xor(pv, 8, 64);
            pv += __shfl_xor(pv, 16, 64); pv += __shfl_xor(pv, 32, 64);
            if (lane == 0) crow[cg] = 0.125f * (pv + wsum * sv) + sb;
        }
    }
    __syncthreads();

    // dot phase: 16 lanes per pixel, 4 pixels per float4 instruction
    const float4* x4 = (const float4*)(x + (size_t)(b * NPIX + h * WW) * DD);
    const int f = lane & 15;
    const int pg = lane >> 4;
#pragma unroll
    for (int i = 0; i < 4; ++i) {
        const int pl = i * 4 + pg;
        if (pl < 15) {
            const int p = g * 15 + pl;
            const int cb = c_colband[p];
            const float4 xv = x4[p * 16 + f];
            const float4 gv = ((const float4*)Gl)[cb * 16 + f];
            float s = xv.x * gv.x + xv.y * gv.y + xv.z * gv.z + xv.w * gv.w;
            s += __shfl_xor(s, 1, 64);
            s += __shfl_xor(s, 2, 64);
            s += __shfl_xor(s, 4, 64);
            s += __shfl_xor(s, 8, 64);
            if (f == 0) attnv[p] = s + crow[cb];
        }
    }
    __syncthreads();

    if (t < 60) {
        const int pix = b * NPIX + h * WW + t;
        const float a = attnv[t];
        const float sg = 1.0f / (1.0f + expf(-a));
        const float gx = logf(sg + 1e-8f);
        const float gr = logf(1.0f - sg + 1e-8f);
        const float ux = noise_x[pix];
        const float ur = noise_r[pix];
        const float nx = -logf(-logf(ux + 1e-8f) + 1e-8f);
        const float nr = -logf(-logf(ur + 1e-8f) + 1e-8f);
        const float INV_T = 1.0f / (0.03f + 1e-8f);
        const float A = (gx + nx) * INV_T;
        const float Rr = (gr + nr) * INV_T;
        out[pix] = 1.0f / (1.0f + expf(Rr - A));
    }
}

extern "C" void kernel_launch(void* const* d_in, const int* in_sizes, int n_in,
                              void* d_out, int out_size, void* d_ws, size_t ws_size,
                              hipStream_t stream)
{
    const float* x       = (const float*)d_in[0];
    const float* qk_w    = (const float*)d_in[1];
    const float* qk_b    = (const float*)d_in[2];
    const float* score_w = (const float*)d_in[3];
    const float* score_b = (const float*)d_in[4];
    const float* noise_x = (const float*)d_in[5];
    const float* noise_r = (const float*)d_in[6];
    float* out = (float*)d_out;

    float* bandsums = (float*)d_ws;             // 64*8*20*64 = 655360 floats
    float* ET_ws = bandsums + 655360;           // 4096
    float* u_ws  = ET_ws + 4096;                // 64
    float* v_ws  = u_ws + 64;                   // 64
    float* s_ws  = v_ws + 64;                   // 1
    // total ~2.64 MB (< 3.375 MB proven-safe footprint); fully overwritten, no memset

    k1_pool_E<<<576, 256, 0, stream>>>(x, qk_w, qk_b, bandsums, ET_ws, u_ws, v_ws, s_ws);
    k2_mask<<<BB * HH, 256, 0, stream>>>(x, score_w, score_b, bandsums, ET_ws, u_ws, v_ws, s_ws,
                                         noise_x, noise_r, out);
}

// Round 4
// 108.979 us; speedup vs baseline: 1.1814x; 1.1814x over previous
//
#include <hip/hip_runtime.h>
#include <math.h>

#define BB 64
#define HH 30
#define WW 60
#define DD 64
#define NPIX 1800
#define NREG 76   // 50 s0 (5x10 regions of 6x6 px) + 18 s1 (3x6 of 10x10) + 8 s2 (2x4 of 15x15)

// 16 col-bands / 8 row-bands = common refinement of the three grids
__constant__ int c_rowband[HH] = {0,0,0,0,0,0, 1,1,1,1, 2,2, 3,3,3, 4,4,4, 5,5, 6,6,6,6, 7,7,7,7,7,7};
__constant__ int c_colband[WW] = {0,0,0,0,0,0, 1,1,1,1, 2,2, 3,3,3, 4,4,4, 5,5, 6,6,6,6, 7,7,7,7,7,7,
                                  8,8,8,8,8,8, 9,9,9,9, 10,10, 11,11,11, 12,12,12, 13,13, 14,14,14,14, 15,15,15,15,15,15};
// colband -> s0/s1 col-region index
__constant__ int c_s0col[16] = {0,1,1,2,2,3,3,4,5,6,6,7,7,8,8,9};
__constant__ int c_s1col[16] = {0,0,1,1,1,1,2,2,3,3,4,4,4,4,5,5};
// rowband -> s0/s1 row-region index
__constant__ int c_s0row[8] = {0,1,1,2,2,3,3,4};
__constant__ int c_s1row[8] = {0,0,1,1,1,1,2,2};

// ---------------- K1: per-row pooling into region sums (blocks 0..1919, R2-proven)
// ----------------     + E/u/v/s weight precompute (blocks 1920..1983, R3-proven)
__global__ __launch_bounds__(256) void ka_pool(
    const float* __restrict__ x, const float* __restrict__ qk_w,
    const float* __restrict__ qk_b, float* __restrict__ psum,
    float* __restrict__ ET_ws, float* __restrict__ u_ws,
    float* __restrict__ v_ws, float* __restrict__ s_ws)
{
    const int t = threadIdx.x;

    if (blockIdx.x >= BB * HH) {
        // ET[e][d] = E[d][e] = sum_j Wq[j][d] * Wk[j][e]  (qk_w rows 0..63 = Wq, 64..127 = Wk)
        const int e = blockIdx.x - BB * HH;
        if (t < 64) {
            float acc = 0.f;
#pragma unroll 8
            for (int jj = 0; jj < 64; ++jj)
                acc += qk_w[jj * 64 + t] * qk_w[(64 + jj) * 64 + e];
            ET_ws[e * 64 + t] = acc;
        } else if (e == 0 && t >= 64 && t < 128) {   // u[d] = Wq^T bk
            const int d = t - 64;
            float acc = 0.f;
            for (int jj = 0; jj < 64; ++jj) acc += qk_w[jj * 64 + d] * qk_b[64 + jj];
            u_ws[d] = acc;
        } else if (e == 0 && t >= 128 && t < 192) {  // v[e] = Wk^T bq
            const int e2 = t - 128;
            float acc = 0.f;
            for (int jj = 0; jj < 64; ++jj) acc += qk_w[(64 + jj) * 64 + e2] * qk_b[jj];
            v_ws[e2] = acc;
        } else if (e == 0 && t == 192) {             // s = bq . bk
            float acc = 0.f;
            for (int jj = 0; jj < 64; ++jj) acc += qk_b[jj] * qk_b[64 + jj];
            s_ws[0] = acc;
        }
        return;
    }

    const int b = blockIdx.x / HH;
    const int h = blockIdx.x % HH;
    const int j = t & 63;
    const int g = t >> 6;

    const float* xrow = x + ((size_t)(b * NPIX + h * WW) + g * 15) * DD;
    float v[15];
#pragma unroll
    for (int i = 0; i < 15; ++i) v[i] = xrow[i * DD + j];

    float a0, a1, a2, a3;   // 4 colband sums within this wave's 15-px quarter
    if ((g & 1) == 0) {     // widths 6,4,2,3
        a0 = ((v[0]+v[1])+(v[2]+v[3]))+(v[4]+v[5]);
        a1 = (v[6]+v[7])+(v[8]+v[9]);
        a2 = v[10]+v[11];
        a3 = (v[12]+v[13])+v[14];
    } else {                // widths 3,2,4,6
        a0 = (v[0]+v[1])+v[2];
        a1 = v[3]+v[4];
        a2 = (v[5]+v[6])+(v[7]+v[8]);
        a3 = ((v[9]+v[10])+(v[11]+v[12]))+(v[13]+v[14]);
    }

    const float s0m = a1 + a2;
    const float s10 = a0 + a1;
    const float s11 = a2 + a3;
    const float s2  = s10 + s11;

    const int r0 = (h / 6) * 10;
    const int r1 = 50 + (h / 10) * 6;
    const int r2 = 68 + (h / 15) * 4;
    const int c0a = c_s0col[4*g], c0b = c_s0col[4*g+1], c0c = c_s0col[4*g+3];
    const int c1a = c_s1col[4*g], c1b = c_s1col[4*g+2];

    float* pb = psum + (size_t)b * NREG * 64 + j;
    atomicAdd(pb + (r0 + c0a) * 64, a0);
    atomicAdd(pb + (r0 + c0b) * 64, s0m);
    atomicAdd(pb + (r0 + c0c) * 64, a3);
    atomicAdd(pb + (r1 + c1a) * 64, s10);
    atomicAdd(pb + (r1 + c1b) * 64, s11);
    atomicAdd(pb + (r2 + g) * 64, s2);
}

// ---------------- K2: per-(b,rowband) cell vectors G + offsets c ----------------
// grid = BB*8, block = 256. ET held in per-lane registers; inner loop is
// 16 uniform ds_read_b128 + 64 reg-FMAs per cell. Each cell computed exactly once.
__global__ __launch_bounds__(256) void kb_G(
    const float* __restrict__ score_w, const float* __restrict__ score_b,
    const float* __restrict__ psum, const float* __restrict__ ET_ws,
    const float* __restrict__ u_ws, const float* __restrict__ v_ws,
    const float* __restrict__ s_ws, float* __restrict__ G, float* __restrict__ cc)
{
    __shared__ float ETs[4096];     // 16 KB
    __shared__ float XC[16 * 64];   // 4 KB
    __shared__ float ul[64], vl[64];

    const int b = blockIdx.x >> 3;
    const int rb = blockIdx.x & 7;
    const int t = threadIdx.x;
    const int lane = t & 63;
    const int g = t >> 6;

    for (int i = t; i < 4096; i += 256) ETs[i] = ET_ws[i];
    if (t < 64) ul[t] = u_ws[t];
    else if (t < 128) vl[t - 64] = v_ws[t - 64];

    const float w0n = score_w[0] * (1.0f / 36.0f);
    const float w1n = score_w[1] * (1.0f / 100.0f);
    const float w2n = score_w[2] * (1.0f / 225.0f);
    const float* pb = psum + (size_t)b * NREG * 64;
    const int r0 = 10 * c_s0row[rb];
    const int r1 = 50 + 6 * c_s1row[rb];
    const int r2 = 68 + 4 * (rb >> 2);
    for (int i = t; i < 16 * 64; i += 256) {
        const int cb = i >> 6, d = i & 63;
        XC[i] = w0n * pb[(r0 + c_s0col[cb]) * 64 + d]
              + w1n * pb[(r1 + c_s1col[cb]) * 64 + d]
              + w2n * pb[(r2 + (cb >> 2)) * 64 + d];
    }
    __syncthreads();

    float et[64];
#pragma unroll
    for (int e = 0; e < 64; ++e) et[e] = ETs[e * 64 + lane];  // 2-way aliasing = free

    const float wsum = score_w[0] + score_w[1] + score_w[2];
    const float sv = s_ws[0];
    const float sb = score_b[0];
    const float uval = ul[lane];
    const float vval = vl[lane];

#pragma unroll
    for (int ci = 0; ci < 4; ++ci) {
        const int cb = g * 4 + ci;
        const float4* xc4 = (const float4*)(XC + cb * 64);
        float acc = 0.f;
#pragma unroll
        for (int q = 0; q < 16; ++q) {
            const float4 xv = xc4[q];     // wave-uniform -> broadcast
            acc += xv.x * et[4*q] + xv.y * et[4*q+1] + xv.z * et[4*q+2] + xv.w * et[4*q+3];
        }
        G[(size_t)b * 8192 + rb * 1024 + cb * 64 + lane] = 0.125f * (acc + wsum * uval);

        float pv = vval * XC[cb * 64 + lane];
        pv += __shfl_xor(pv, 1, 64);  pv += __shfl_xor(pv, 2, 64);
        pv += __shfl_xor(pv, 4, 64);  pv += __shfl_xor(pv, 8, 64);
        pv += __shfl_xor(pv, 16, 64); pv += __shfl_xor(pv, 32, 64);
        if (lane == 0) cc[b * 128 + rb * 16 + cb] = 0.125f * (pv + wsum * sv) + sb;
    }
}

// ---------------- K3: per-pixel dot + gumbel-sigmoid mask (R2-proven) ----------------
__global__ __launch_bounds__(256) void kc_mask(
    const float* __restrict__ x, const float* __restrict__ G,
    const float* __restrict__ cc, const float* __restrict__ noise_x,
    const float* __restrict__ noise_r, float* __restrict__ out)
{
    __shared__ float Grow[1024];
    __shared__ float crow[16];
    __shared__ float attnv[64];
    __shared__ int cbt[64];

    const int b = blockIdx.x / HH;
    const int h = blockIdx.x % HH;
    const int t = threadIdx.x;
    const int lane = t & 63;
    const int g = t >> 6;
    const int rb = c_rowband[h];

    ((float4*)Grow)[t] = ((const float4*)(G + (size_t)b * 8192 + rb * 1024))[t];
    if (t < 16) crow[t] = cc[b * 128 + rb * 16 + t];
    if (t < 60) cbt[t] = c_colband[t];
    __syncthreads();

    const float4* x4 = (const float4*)(x + (size_t)(b * NPIX + h * WW) * DD);
    const int f = lane & 15;
    const int pg = lane >> 4;
#pragma unroll
    for (int i = 0; i < 4; ++i) {
        const int pl = i * 4 + pg;
        if (pl < 15) {
            const int p = g * 15 + pl;
            const int cb = cbt[p];
            const float4 xv = x4[p * 16 + f];
            const float4 gv = ((const float4*)Grow)[cb * 16 + f];
            float s = xv.x * gv.x + xv.y * gv.y + xv.z * gv.z + xv.w * gv.w;
            s += __shfl_xor(s, 1, 64);
            s += __shfl_xor(s, 2, 64);
            s += __shfl_xor(s, 4, 64);
            s += __shfl_xor(s, 8, 64);
            if (f == 0) attnv[p] = s + crow[cb];
        }
    }
    __syncthreads();

    if (t < 60) {
        const int pix = b * NPIX + h * WW + t;
        const float a = attnv[t];
        const float sg = 1.0f / (1.0f + expf(-a));
        const float gx = logf(sg + 1e-8f);
        const float gr = logf(1.0f - sg + 1e-8f);
        const float ux = noise_x[pix];
        const float ur = noise_r[pix];
        const float nx = -logf(-logf(ux + 1e-8f) + 1e-8f);
        const float nr = -logf(-logf(ur + 1e-8f) + 1e-8f);
        const float INV_T = 1.0f / (0.03f + 1e-8f);
        const float A = (gx + nx) * INV_T;
        const float R = (gr + nr) * INV_T;
        out[pix] = 1.0f / (1.0f + expf(R - A));
    }
}

extern "C" void kernel_launch(void* const* d_in, const int* in_sizes, int n_in,
                              void* d_out, int out_size, void* d_ws, size_t ws_size,
                              hipStream_t stream)
{
    const float* x       = (const float*)d_in[0];
    const float* qk_w    = (const float*)d_in[1];
    const float* qk_b    = (const float*)d_in[2];
    const float* score_w = (const float*)d_in[3];
    const float* score_b = (const float*)d_in[4];
    const float* noise_x = (const float*)d_in[5];
    const float* noise_r = (const float*)d_in[6];
    float* out = (float*)d_out;

    float* psum  = (float*)d_ws;                     // 64*76*64  = 311296 floats (1.2 MB)
    float* G     = psum + (size_t)BB * NREG * 64;    // 64*128*64 = 524288 floats (2 MB)
    float* cc    = G + (size_t)BB * 128 * 64;        // 8192
    float* ET_ws = cc + BB * 128;                    // 4096
    float* u_ws  = ET_ws + 4096;                     // 64
    float* v_ws  = u_ws + 64;                        // 64
    float* s_ws  = v_ws + 64;                        // 1
    // total ~3.4 MB

    hipMemsetAsync(psum, 0, (size_t)BB * NREG * 64 * sizeof(float), stream);
    ka_pool<<<BB * HH + 64, 256, 0, stream>>>(x, qk_w, qk_b, psum, ET_ws, u_ws, v_ws, s_ws);
    kb_G<<<BB * 8, 256, 0, stream>>>(score_w, score_b, psum, ET_ws, u_ws, v_ws, s_ws, G, cc);
    kc_mask<<<BB * HH, 256, 0, stream>>>(x, G, cc, noise_x, noise_r, out);
}